// Round 12
// baseline (842.905 us; speedup 1.0000x reference)
//
#include <hip/hip_runtime.h>
#include <type_traits>

typedef _Float16 f16;
typedef _Float16 f16x4 __attribute__((ext_vector_type(4)));
typedef _Float16 f16x8 __attribute__((ext_vector_type(8)));
typedef float    f32x4 __attribute__((ext_vector_type(4)));

constexpr int TT = 512;   // timesteps
constexpr int FF = 64;    // input features
constexpr int H1 = 128;   // layer-1 hidden (512 gate cols)
constexpr int H2 = 64;    // layer-2 hidden (256 gate cols)
constexpr int D1 = 25;    // dense-1 width
constexpr int S1 = 136;   // h1 LDS row stride (f16)
constexpr int S2 = 72;    // h2 LDS row stride
constexpr int XC = 8;     // x timesteps per staged LDS chunk (fallback path)
constexpr float L2E = 1.44269504088896f;

// z pre-scaled by log2(e) at weight-load time: sigmoid = rcp(1 + 2^-z).
__device__ __forceinline__ float sigm2(float z) {
    return __builtin_amdgcn_rcpf(1.f + __builtin_amdgcn_exp2f(-z));
}

__device__ __forceinline__ f32x4 mfma16(f16x8 a, f16x8 b, f32x4 c) {
    return __builtin_amdgcn_mfma_f32_16x16x32_f16(a, b, c, 0, 0, 0);
}

__device__ __forceinline__ void gl_lds16(const f16* g, f16* l) {
    __builtin_amdgcn_global_load_lds(
        (const __attribute__((address_space(1))) unsigned int*)g,
        (__attribute__((address_space(3))) unsigned int*)l, 16, 0, 0);
}

// Shared xw layout: lane (w,quad,lid) of batch-group bg at step t owns 16 f16
// (g0..g3 x r0..r3) at this offset (in f16 units). Pre-GEMM writes it,
// recurrent kernel C-inits from it -- identical formula on both sides.
__device__ __forceinline__ size_t xw_off(int bg, int t, int w, int quad, int lid) {
    return ((((size_t)(bg * 512 + t) * 8 + w) * 4 + quad) * 16 + lid) * 16;
}

// ================= full-chip pre-GEMM: xw = (x @ W1 + b1) * gate_scale ======
// 2048 blocks x 512 thr: block (bg, tc) does 16 batch rows x 8 timesteps.
// Same verified operand mapping as the recurrent kernel: weights = A operand
// (lane holds col n=128g+16w+lid, rows k=32c+quad*8+e), x = B operand
// (lane holds x[batch=lid][k=32c+quad*8+e]); D[m=quad*4+r][n=lid].
__global__ __launch_bounds__(512, 4)
void xw_gemm(const float* __restrict__ x, const float* __restrict__ W1,
             const float* __restrict__ b1, f16* __restrict__ xw)
{
    const int tid  = threadIdx.x;
    const int w    = tid >> 6;
    const int lane = tid & 63;
    const int quad = lane >> 4;
    const int lid  = lane & 15;
    const int bg   = blockIdx.x & 31;
    const int tc   = blockIdx.x >> 5;   // 0..63

    f16x8 wa[4][2];
    f32x4 bsp[4];
#pragma unroll
    for (int g = 0; g < 4; ++g) {
        const float sc = (g == 2) ? 1.f : L2E;
        const int n = 128 * g + 16 * w + lid;
#pragma unroll
        for (int rr = 0; rr < 4; ++rr)
            bsp[g][rr] = b1[128 * g + 16 * w + quad * 4 + rr] * sc;
#pragma unroll
        for (int c = 0; c < 2; ++c) {
            f16x8 f;
#pragma unroll
            for (int e = 0; e < 8; ++e)
                f[e] = (f16)(W1[(32 * c + quad * 8 + e) * 512 + n] * sc);
            wa[g][c] = f;
        }
    }

    for (int tt = 0; tt < 8; ++tt) {
        const int t = tc * 8 + tt;
        const float* xr = x + ((size_t)(bg * 16 + lid) * TT + t) * FF + quad * 8;
        const float4 p0 = *(const float4*)xr;
        const float4 p1 = *(const float4*)(xr + 4);
        const float4 p2 = *(const float4*)(xr + 32);
        const float4 p3 = *(const float4*)(xr + 36);
        f16x8 xb0, xb1;
        xb0[0]=(f16)p0.x; xb0[1]=(f16)p0.y; xb0[2]=(f16)p0.z; xb0[3]=(f16)p0.w;
        xb0[4]=(f16)p1.x; xb0[5]=(f16)p1.y; xb0[6]=(f16)p1.z; xb0[7]=(f16)p1.w;
        xb1[0]=(f16)p2.x; xb1[1]=(f16)p2.y; xb1[2]=(f16)p2.z; xb1[3]=(f16)p2.w;
        xb1[4]=(f16)p3.x; xb1[5]=(f16)p3.y; xb1[6]=(f16)p3.z; xb1[7]=(f16)p3.w;

        f32x4 acc[4];
#pragma unroll
        for (int g = 0; g < 4; ++g) {
            f32x4 a = mfma16(wa[g][0], xb0, bsp[g]);
            acc[g] = mfma16(wa[g][1], xb1, a);
        }
        f16x8 s01, s23;
#pragma unroll
        for (int r = 0; r < 4; ++r) {
            s01[r]     = (f16)acc[0][r];
            s01[4 + r] = (f16)acc[1][r];
            s23[r]     = (f16)acc[2][r];
            s23[4 + r] = (f16)acc[3][r];
        }
        f16* dst = xw + xw_off(bg, t, w, quad, lid);
        *(f16x8*)dst = s01;
        *(f16x8*)(dst + 8) = s23;
    }
}

// ================= recurrent kernel (new path): xw-fed layer 1 ==============
// 32 blocks x 768 threads (12 waves, 3/SIMD). Waves 0-7: layer-1 step i,
// C-init = precomputed xw (2 dwordx4 prefetched one step ahead), MFMA chain
// only 4 chunks (h1 @ U1). Waves 8-11: layer-2 step i-1, unchanged. One
// barrier per step, compile-time ping-pong parity, operand-swapped MFMA.
__global__ __launch_bounds__(768, 3)
void lstm_pipe10(const f16* __restrict__ xw, const float* __restrict__ U1,
                 const float* __restrict__ W2, const float* __restrict__ U2,
                 const float* __restrict__ b2, const float* __restrict__ Wd1,
                 const float* __restrict__ bd1,const float* __restrict__ Wd2,
                 const float* __restrict__ bd2, float* __restrict__ out)
{
    const int tid  = threadIdx.x;
    const int w    = tid >> 6;      // wave 0..11
    const int lane = tid & 63;
    const int quad = lane >> 4;
    const int lid  = lane & 15;
    const int bg   = blockIdx.x;
    const int b0   = bg * 16;
    const bool isL1 = (w < 8);
    const int  j    = isL1 ? w : (w - 8);

    __shared__ __align__(16) f16 h1b[2][16][S1];
    __shared__ __align__(16) f16 h2b[2][16][S2];
    __shared__ float h2f[16][H2];
    __shared__ float dsh[16][D1];

    for (int i = tid; i < 2 * 16 * S1 / 2; i += 768) ((unsigned*)h1b)[i] = 0u;
    for (int i = tid; i < 2 * 16 * S2 / 2; i += 768) ((unsigned*)h2b)[i] = 0u;

    f16x8 wt[4][6];
    f32x4 bsp[4];                // used by L2 waves only (L1 bias is in xw)
    float cs[4] = {0.f, 0.f, 0.f, 0.f};
    f16x8 xw01, xw23;            // L1 waves: current step's C-init (prefetched)

    if (isL1) {
#pragma unroll
        for (int g = 0; g < 4; ++g) {
            const float sc = (g == 2) ? 1.f : L2E;
            const int n = 128 * g + 16 * w + lid;
#pragma unroll
            for (int c = 0; c < 4; ++c) {
                f16x8 f;
#pragma unroll
                for (int e = 0; e < 8; ++e)
                    f[e] = (f16)(U1[(32 * c + quad * 8 + e) * 512 + n] * sc);
                wt[g][c] = f;
            }
        }
        const f16* p0 = xw + xw_off(bg, 0, w, quad, lid);
        xw01 = *(const f16x8*)p0;
        xw23 = *(const f16x8*)(p0 + 8);
    } else {
#pragma unroll
        for (int g = 0; g < 4; ++g) {
            const float sc = (g == 2) ? 1.f : L2E;
            const int n = 64 * g + 16 * j + lid;
#pragma unroll
            for (int rr = 0; rr < 4; ++rr)
                bsp[g][rr] = b2[64 * g + 16 * j + quad * 4 + rr] * sc;
#pragma unroll
            for (int c = 0; c < 4; ++c) {
                f16x8 f;
#pragma unroll
                for (int e = 0; e < 8; ++e)
                    f[e] = (f16)(W2[(32 * c + quad * 8 + e) * 256 + n] * sc);
                wt[g][c] = f;
            }
#pragma unroll
            for (int c = 0; c < 2; ++c) {
                f16x8 f;
#pragma unroll
                for (int e = 0; e < 8; ++e)
                    f[e] = (f16)(U2[(32 * c + quad * 8 + e) * 256 + n] * sc);
                wt[g][4 + c] = f;
            }
        }
    }
    __syncthreads();

    auto step = [&](auto parc, int i) {
        constexpr int PAR = decltype(parc)::value;
        constexpr int PR = PAR ^ 1;   // h1[i-1]
        constexpr int PW = PAR;       // h1[i]
        constexpr int QR = PAR;       // h2[i-2]
        constexpr int QW = PAR ^ 1;   // h2[i-1]
        if (isL1) {
            f16x8 fr0 = *(const f16x8*)&h1b[PR][lid][quad * 8];
            f16x8 fr1 = *(const f16x8*)&h1b[PR][lid][32 + quad * 8];
            f16x8 fr2 = *(const f16x8*)&h1b[PR][lid][64 + quad * 8];
            f16x8 fr3 = *(const f16x8*)&h1b[PR][lid][96 + quad * 8];
            f32x4 acc[4];
#pragma unroll
            for (int r = 0; r < 4; ++r) {
                acc[0][r] = (float)xw01[r];
                acc[1][r] = (float)xw01[4 + r];
                acc[2][r] = (float)xw23[r];
                acc[3][r] = (float)xw23[4 + r];
            }
            if (i + 1 < TT) {   // prefetch next step's C-init (full step to land)
                const f16* p = xw + xw_off(bg, i + 1, w, quad, lid);
                xw01 = *(const f16x8*)p;
                xw23 = *(const f16x8*)(p + 8);
            }
#pragma unroll
            for (int g = 0; g < 4; ++g) {
                acc[g] = mfma16(wt[g][0], fr0, acc[g]);
                acc[g] = mfma16(wt[g][1], fr1, acc[g]);
                acc[g] = mfma16(wt[g][2], fr2, acc[g]);
                acc[g] = mfma16(wt[g][3], fr3, acc[g]);
            }
            f16x4 hp;
#pragma unroll
            for (int r = 0; r < 4; ++r) {
                const float ig = sigm2(acc[0][r]);
                const float fg = sigm2(acc[1][r]);
                const float gg = fmaxf(acc[2][r], 0.f);
                const float og = sigm2(acc[3][r]);
                const float cc = fg * cs[r] + ig * gg;
                cs[r] = cc;
                hp[r] = (f16)(og * fmaxf(cc, 0.f));
            }
            *(f16x4*)&h1b[PW][lid][16 * w + quad * 4] = hp;
        } else {
            if (i >= 1) {
                f16x8 fr0 = *(const f16x8*)&h1b[PR][lid][quad * 8];
                f16x8 fr1 = *(const f16x8*)&h1b[PR][lid][32 + quad * 8];
                f16x8 fr2 = *(const f16x8*)&h1b[PR][lid][64 + quad * 8];
                f16x8 fr3 = *(const f16x8*)&h1b[PR][lid][96 + quad * 8];
                f16x8 fr4 = *(const f16x8*)&h2b[QR][lid][quad * 8];
                f16x8 fr5 = *(const f16x8*)&h2b[QR][lid][32 + quad * 8];
                f32x4 acc[4];
#pragma unroll
                for (int g = 0; g < 4; ++g) {
                    f32x4 a = mfma16(wt[g][0], fr0, bsp[g]);
                    a = mfma16(wt[g][1], fr1, a);
                    a = mfma16(wt[g][2], fr2, a);
                    a = mfma16(wt[g][3], fr3, a);
                    a = mfma16(wt[g][4], fr4, a);
                    a = mfma16(wt[g][5], fr5, a);
                    acc[g] = a;
                }
                f16x4 hp;
#pragma unroll
                for (int r = 0; r < 4; ++r) {
                    const float ig = sigm2(acc[0][r]);
                    const float fg = sigm2(acc[1][r]);
                    const float gg = fmaxf(acc[2][r], 0.f);
                    const float og = sigm2(acc[3][r]);
                    const float cc = fg * cs[r] + ig * gg;
                    cs[r] = cc;
                    hp[r] = (f16)(og * fmaxf(cc, 0.f));
                }
                *(f16x4*)&h2b[QW][lid][16 * j + quad * 4] = hp;
            }
        }
    };

    for (int ii = 0; ii < TT; ii += 2) {
        step(std::integral_constant<int, 0>{}, ii);
        __syncthreads();
        step(std::integral_constant<int, 1>{}, ii + 1);
        __syncthreads();
    }

    // final pipeline step i=TT (even): L2 consumes h1[TT-1], exports h2 f32
    if (!isL1) {
        f16x8 fr0 = *(const f16x8*)&h1b[1][lid][quad * 8];
        f16x8 fr1 = *(const f16x8*)&h1b[1][lid][32 + quad * 8];
        f16x8 fr2 = *(const f16x8*)&h1b[1][lid][64 + quad * 8];
        f16x8 fr3 = *(const f16x8*)&h1b[1][lid][96 + quad * 8];
        f16x8 fr4 = *(const f16x8*)&h2b[0][lid][quad * 8];
        f16x8 fr5 = *(const f16x8*)&h2b[0][lid][32 + quad * 8];
        f32x4 acc[4];
#pragma unroll
        for (int g = 0; g < 4; ++g) {
            f32x4 a = mfma16(wt[g][0], fr0, bsp[g]);
            a = mfma16(wt[g][1], fr1, a);
            a = mfma16(wt[g][2], fr2, a);
            a = mfma16(wt[g][3], fr3, a);
            a = mfma16(wt[g][4], fr4, a);
            a = mfma16(wt[g][5], fr5, a);
            acc[g] = a;
        }
        float4 ho;
#pragma unroll
        for (int r = 0; r < 4; ++r) {
            const float ig = sigm2(acc[0][r]);
            const float fg = sigm2(acc[1][r]);
            const float gg = fmaxf(acc[2][r], 0.f);
            const float og = sigm2(acc[3][r]);
            const float cc = fg * cs[r] + ig * gg;
            (&ho.x)[r] = og * fmaxf(cc, 0.f);
        }
        *(float4*)&h2f[lid][16 * j + quad * 4] = ho;
    }
    __syncthreads();

    for (int idx = tid; idx < 16 * D1; idx += 768) {
        const int bq = idx / D1, p = idx % D1;
        float d = bd1[p];
#pragma unroll
        for (int k = 0; k < H2; ++k) d += h2f[bq][k] * Wd1[k * D1 + p];
        dsh[bq][p] = d * Wd2[p];
    }
    __syncthreads();
    if (tid < 16) {
        float o = bd2[0];
#pragma unroll
        for (int p = 0; p < D1; ++p) o += dsh[tid][p];
        out[b0 + tid] = o;
    }
}

// ================= fallback path (R11, passing at 618 us) ===================
__global__ void cvt_x_kernel(const float* __restrict__ x, f16* __restrict__ xh) {
    const size_t i = ((size_t)blockIdx.x * blockDim.x + threadIdx.x) * 4;
    const float4 v = *(const float4*)(x + i);
    f16x4 h; h[0] = (f16)v.x; h[1] = (f16)v.y; h[2] = (f16)v.z; h[3] = (f16)v.w;
    *(f16x4*)(xh + i) = h;
}

__global__ __launch_bounds__(768, 3)
void lstm_pipe9(const f16* __restrict__ xh, const float* __restrict__ W1,
                const float* __restrict__ U1, const float* __restrict__ b1,
                const float* __restrict__ W2, const float* __restrict__ U2,
                const float* __restrict__ b2, const float* __restrict__ Wd1,
                const float* __restrict__ bd1,const float* __restrict__ Wd2,
                const float* __restrict__ bd2, float* __restrict__ out)
{
    const int tid  = threadIdx.x;
    const int w    = tid >> 6;
    const int lane = tid & 63;
    const int quad = lane >> 4;
    const int lid  = lane & 15;
    const int b0   = blockIdx.x * 16;
    const bool isL1 = (w < 8);
    const int  j    = isL1 ? w : (w - 8);

    __shared__ __align__(16) f16 h1b[2][16][S1];
    __shared__ __align__(16) f16 h2b[2][16][S2];
    __shared__ __align__(16) f16 xlds[2][XC * 8 * 16 * 8];
    __shared__ float h2f[16][H2];
    __shared__ float dsh[16][D1];

    for (int i = tid; i < 2 * 16 * S1 / 2; i += 768) ((unsigned*)h1b)[i] = 0u;
    for (int i = tid; i < 2 * 16 * S2 / 2; i += 768) ((unsigned*)h2b)[i] = 0u;

    for (int s = tid; s < XC * 8 * 16; s += 768) {
        const int tl = s >> 7, fs = (s >> 4) & 7, row = s & 15;
        const f16* gp = xh + ((size_t)(b0 + row) * TT + tl) * FF + fs * 8;
        gl_lds16(gp, &xlds[0][(s >> 6) * 512]);
    }

    f16x8 wt[4][6];
    f32x4 bsp[4];
    float cs[4] = {0.f, 0.f, 0.f, 0.f};

    if (isL1) {
#pragma unroll
        for (int g = 0; g < 4; ++g) {
            const float sc = (g == 2) ? 1.f : L2E;
            const int n = 128 * g + 16 * w + lid;
#pragma unroll
            for (int rr = 0; rr < 4; ++rr)
                bsp[g][rr] = b1[128 * g + 16 * w + quad * 4 + rr] * sc;
#pragma unroll
            for (int c = 0; c < 4; ++c) {
                f16x8 f;
#pragma unroll
                for (int e = 0; e < 8; ++e)
                    f[e] = (f16)(U1[(32 * c + quad * 8 + e) * 512 + n] * sc);
                wt[g][c] = f;
            }
#pragma unroll
            for (int c = 0; c < 2; ++c) {
                f16x8 f;
#pragma unroll
                for (int e = 0; e < 8; ++e)
                    f[e] = (f16)(W1[(32 * c + quad * 8 + e) * 512 + n] * sc);
                wt[g][4 + c] = f;
            }
        }
    } else {
#pragma unroll
        for (int g = 0; g < 4; ++g) {
            const float sc = (g == 2) ? 1.f : L2E;
            const int n = 64 * g + 16 * j + lid;
#pragma unroll
            for (int rr = 0; rr < 4; ++rr)
                bsp[g][rr] = b2[64 * g + 16 * j + quad * 4 + rr] * sc;
#pragma unroll
            for (int c = 0; c < 4; ++c) {
                f16x8 f;
#pragma unroll
                for (int e = 0; e < 8; ++e)
                    f[e] = (f16)(W2[(32 * c + quad * 8 + e) * 256 + n] * sc);
                wt[g][c] = f;
            }
#pragma unroll
            for (int c = 0; c < 2; ++c) {
                f16x8 f;
#pragma unroll
                for (int e = 0; e < 8; ++e)
                    f[e] = (f16)(U2[(32 * c + quad * 8 + e) * 256 + n] * sc);
                wt[g][4 + c] = f;
            }
        }
    }
    __syncthreads();

    auto step = [&](auto parc, int i) {
        constexpr int PAR = decltype(parc)::value;
        constexpr int PR = PAR ^ 1;
        constexpr int PW = PAR;
        constexpr int QR = PAR;
        constexpr int QW = PAR ^ 1;
        if (isL1) {
            const f16* xc = &xlds[(i >> 3) & 1][(i & 7) * 1024];
            f16x8 fr0 = *(const f16x8*)&h1b[PR][lid][quad * 8];
            f16x8 fr1 = *(const f16x8*)&h1b[PR][lid][32 + quad * 8];
            f16x8 fr2 = *(const f16x8*)&h1b[PR][lid][64 + quad * 8];
            f16x8 fr3 = *(const f16x8*)&h1b[PR][lid][96 + quad * 8];
            f16x8 xf0 = *(const f16x8*)&xc[(quad * 16 + lid) * 8];
            f16x8 xf1 = *(const f16x8*)&xc[((4 + quad) * 16 + lid) * 8];
            f32x4 acc[4];
#pragma unroll
            for (int g = 0; g < 4; ++g) {
                f32x4 a = mfma16(wt[g][0], fr0, bsp[g]);
                a = mfma16(wt[g][1], fr1, a);
                a = mfma16(wt[g][2], fr2, a);
                a = mfma16(wt[g][3], fr3, a);
                a = mfma16(wt[g][4], xf0, a);
                a = mfma16(wt[g][5], xf1, a);
                acc[g] = a;
            }
            f16x4 hp;
#pragma unroll
            for (int r = 0; r < 4; ++r) {
                const float ig = sigm2(acc[0][r]);
                const float fg = sigm2(acc[1][r]);
                const float gg = fmaxf(acc[2][r], 0.f);
                const float og = sigm2(acc[3][r]);
                const float cc = fg * cs[r] + ig * gg;
                cs[r] = cc;
                hp[r] = (f16)(og * fmaxf(cc, 0.f));
            }
            *(f16x4*)&h1b[PW][lid][16 * w + quad * 4] = hp;
        } else {
            if (i >= 1) {
                f16x8 fr0 = *(const f16x8*)&h1b[PR][lid][quad * 8];
                f16x8 fr1 = *(const f16x8*)&h1b[PR][lid][32 + quad * 8];
                f16x8 fr2 = *(const f16x8*)&h1b[PR][lid][64 + quad * 8];
                f16x8 fr3 = *(const f16x8*)&h1b[PR][lid][96 + quad * 8];
                f16x8 fr4 = *(const f16x8*)&h2b[QR][lid][quad * 8];
                f16x8 fr5 = *(const f16x8*)&h2b[QR][lid][32 + quad * 8];
                f32x4 acc[4];
#pragma unroll
                for (int g = 0; g < 4; ++g) {
                    f32x4 a = mfma16(wt[g][0], fr0, bsp[g]);
                    a = mfma16(wt[g][1], fr1, a);
                    a = mfma16(wt[g][2], fr2, a);
                    a = mfma16(wt[g][3], fr3, a);
                    a = mfma16(wt[g][4], fr4, a);
                    a = mfma16(wt[g][5], fr5, a);
                    acc[g] = a;
                }
                f16x4 hp;
#pragma unroll
                for (int r = 0; r < 4; ++r) {
                    const float ig = sigm2(acc[0][r]);
                    const float fg = sigm2(acc[1][r]);
                    const float gg = fmaxf(acc[2][r], 0.f);
                    const float og = sigm2(acc[3][r]);
                    const float cc = fg * cs[r] + ig * gg;
                    cs[r] = cc;
                    hp[r] = (f16)(og * fmaxf(cc, 0.f));
                }
                *(f16x4*)&h2b[QW][lid][16 * j + quad * 4] = hp;
            }
        }
    };

    for (int ii = 0; ii < TT; ii += 2) {
        if ((ii & (XC - 1)) == 0 && ii + XC < TT) {
            const int nc = (ii >> 3) + 1;
            f16* dst = xlds[nc & 1];
            for (int s = tid; s < XC * 8 * 16; s += 768) {
                const int tl = s >> 7, fs = (s >> 4) & 7, row = s & 15;
                const f16* gp = xh + ((size_t)(b0 + row) * TT + (nc * XC + tl)) * FF + fs * 8;
                gl_lds16(gp, &dst[(s >> 6) * 512]);
            }
        }
        step(std::integral_constant<int, 0>{}, ii);
        __syncthreads();
        step(std::integral_constant<int, 1>{}, ii + 1);
        __syncthreads();
    }

    if (!isL1) {
        f16x8 fr0 = *(const f16x8*)&h1b[1][lid][quad * 8];
        f16x8 fr1 = *(const f16x8*)&h1b[1][lid][32 + quad * 8];
        f16x8 fr2 = *(const f16x8*)&h1b[1][lid][64 + quad * 8];
        f16x8 fr3 = *(const f16x8*)&h1b[1][lid][96 + quad * 8];
        f16x8 fr4 = *(const f16x8*)&h2b[0][lid][quad * 8];
        f16x8 fr5 = *(const f16x8*)&h2b[0][lid][32 + quad * 8];
        f32x4 acc[4];
#pragma unroll
        for (int g = 0; g < 4; ++g) {
            f32x4 a = mfma16(wt[g][0], fr0, bsp[g]);
            a = mfma16(wt[g][1], fr1, a);
            a = mfma16(wt[g][2], fr2, a);
            a = mfma16(wt[g][3], fr3, a);
            a = mfma16(wt[g][4], fr4, a);
            a = mfma16(wt[g][5], fr5, a);
            acc[g] = a;
        }
        float4 ho;
#pragma unroll
        for (int r = 0; r < 4; ++r) {
            const float ig = sigm2(acc[0][r]);
            const float fg = sigm2(acc[1][r]);
            const float gg = fmaxf(acc[2][r], 0.f);
            const float og = sigm2(acc[3][r]);
            const float cc = fg * cs[r] + ig * gg;
            (&ho.x)[r] = og * fmaxf(cc, 0.f);
        }
        *(float4*)&h2f[lid][16 * j + quad * 4] = ho;
    }
    __syncthreads();

    for (int idx = tid; idx < 16 * D1; idx += 768) {
        const int bq = idx / D1, p = idx % D1;
        float d = bd1[p];
#pragma unroll
        for (int k = 0; k < H2; ++k) d += h2f[bq][k] * Wd1[k * D1 + p];
        dsh[bq][p] = d * Wd2[p];
    }
    __syncthreads();
    if (tid < 16) {
        float o = bd2[0];
#pragma unroll
        for (int p = 0; p < D1; ++p) o += dsh[tid][p];
        out[b0 + tid] = o;
    }
}

extern "C" void kernel_launch(void* const* d_in, const int* in_sizes, int n_in,
                              void* d_out, int out_size, void* d_ws, size_t ws_size,
                              hipStream_t stream) {
    (void)in_sizes; (void)n_in; (void)out_size;
    const float* x   = (const float*)d_in[0];
    const float* W1  = (const float*)d_in[1];
    const float* U1  = (const float*)d_in[2];
    const float* b1  = (const float*)d_in[3];
    const float* W2  = (const float*)d_in[4];
    const float* U2  = (const float*)d_in[5];
    const float* b2  = (const float*)d_in[6];
    const float* Wd1 = (const float*)d_in[7];
    const float* bd1 = (const float*)d_in[8];
    const float* Wd2 = (const float*)d_in[9];
    const float* bd2 = (const float*)d_in[10];
    float* out = (float*)d_out;

    const size_t need = (size_t)512 * 512 * 512 * sizeof(f16);   // 256 MiB xw
    if (ws_size >= need) {
        f16* xwbuf = (f16*)d_ws;
        xw_gemm<<<dim3(2048), dim3(512), 0, stream>>>(x, W1, b1, xwbuf);
        lstm_pipe10<<<dim3(32), dim3(768), 0, stream>>>(
            xwbuf, U1, W2, U2, b2, Wd1, bd1, Wd2, bd2, out);
    } else {
        f16* xh = (f16*)d_ws;    // 32 MiB
        const int nx = 512 * 512 * 64;
        cvt_x_kernel<<<dim3(nx / (256 * 4)), dim3(256), 0, stream>>>(x, xh);
        lstm_pipe9<<<dim3(32), dim3(768), 0, stream>>>(
            xh, W1, U1, b1, W2, U2, b2, Wd1, bd1, Wd2, bd2, out);
    }
}

// Round 13
// 806.942 us; speedup vs baseline: 1.0446x; 1.0446x over previous
//
#include <hip/hip_runtime.h>
#include <type_traits>

typedef _Float16 f16;
typedef _Float16 f16x4 __attribute__((ext_vector_type(4)));
typedef _Float16 f16x8 __attribute__((ext_vector_type(8)));
typedef float    f32x4 __attribute__((ext_vector_type(4)));

constexpr int TT = 512;   // timesteps
constexpr int FF = 64;    // input features
constexpr int H1 = 128;   // layer-1 hidden (512 gate cols)
constexpr int H2 = 64;    // layer-2 hidden (256 gate cols)
constexpr int D1 = 25;    // dense-1 width
constexpr int S1 = 136;   // h1 LDS row stride (f16)
constexpr int S2 = 72;    // h2 LDS row stride
constexpr float L2E = 1.44269504088896f;

// z pre-scaled by log2(e) at weight-load time: sigmoid = rcp(1 + 2^-z).
__device__ __forceinline__ float sigm2(float z) {
    return __builtin_amdgcn_rcpf(1.f + __builtin_amdgcn_exp2f(-z));
}

__device__ __forceinline__ f32x4 mfma16(f16x8 a, f16x8 b, f32x4 c) {
    return __builtin_amdgcn_mfma_f32_16x16x32_f16(a, b, c, 0, 0, 0);
}

// pre-pass: x fp32 -> f16 so the hot loop's x loads are raw B-fragments.
__global__ void cvt_x_kernel(const float* __restrict__ x, f16* __restrict__ xh) {
    const size_t i = ((size_t)blockIdx.x * blockDim.x + threadIdx.x) * 4;
    const float4 v = *(const float4*)(x + i);
    f16x4 h; h[0] = (f16)v.x; h[1] = (f16)v.y; h[2] = (f16)v.z; h[3] = (f16)v.w;
    *(f16x4*)(xh + i) = h;
}

// 32 blocks x 768 threads (12 waves, 3/SIMD). Waves 0-7: layer-1 step i.
// Waves 8-11: layer-2 step i-1. Ping-pong h1/h2 LDS buffers => ONE barrier
// per step; compile-time parity; operand-swapped MFMA (weights = A).
// R13: x fed per-step as raw f16 B-fragments from GLOBAL (2 dwordx4/wave,
// +128B/step, loaded into the same regs after consumption, one full step of
// prefetch distance) -- removes the xlds staging path entirely. LDS read
// burst/step: 72 -> 56 b128 (the convoy bottleneck).
__global__ __launch_bounds__(768, 3)
void lstm_pipe11(const f16* __restrict__ xh, const float* __restrict__ W1,
                 const float* __restrict__ U1, const float* __restrict__ b1,
                 const float* __restrict__ W2, const float* __restrict__ U2,
                 const float* __restrict__ b2, const float* __restrict__ Wd1,
                 const float* __restrict__ bd1,const float* __restrict__ Wd2,
                 const float* __restrict__ bd2, float* __restrict__ out)
{
    const int tid  = threadIdx.x;
    const int w    = tid >> 6;      // wave 0..11
    const int lane = tid & 63;
    const int quad = lane >> 4;
    const int lid  = lane & 15;
    const int b0   = blockIdx.x * 16;
    const bool isL1 = (w < 8);
    const int  j    = isL1 ? w : (w - 8);

    __shared__ __align__(16) f16 h1b[2][16][S1];
    __shared__ __align__(16) f16 h2b[2][16][S2];
    __shared__ float h2f[16][H2];
    __shared__ float dsh[16][D1];

    for (int i = tid; i < 2 * 16 * S1 / 2; i += 768) ((unsigned*)h1b)[i] = 0u;
    for (int i = tid; i < 2 * 16 * S2 / 2; i += 768) ((unsigned*)h2b)[i] = 0u;

    // ---- weight fragments wt[g][c] (A operand): lane holds col n=base+lid,
    // rows k = 32c + quad*8 + e. gates 0,1,3 pre-scaled by log2e.
    // L1 (w<8):  chunks 0..3 = U1 (h1, K=128), 4..5 = W1 (x, K=64)
    // L2 (w>=8): chunks 0..3 = W2 (h1, K=128), 4..5 = U2 (h2, K=64)
    f16x8 wt[4][6];
    f32x4 bsp[4];     // bias for this lane's 4 consecutive gate cols (C-init)
    float cs[4] = {0.f, 0.f, 0.f, 0.f};
    f16x8 xf0, xf1;               // L1: x[t] B-fragment (global-fed)
    const f16* xp = nullptr;      // L1: pointer to x[t+1] fragment

    if (isL1) {
#pragma unroll
        for (int g = 0; g < 4; ++g) {
            const float sc = (g == 2) ? 1.f : L2E;
            const int n = 128 * g + 16 * w + lid;
#pragma unroll
            for (int rr = 0; rr < 4; ++rr)
                bsp[g][rr] = b1[128 * g + 16 * w + quad * 4 + rr] * sc;
#pragma unroll
            for (int c = 0; c < 4; ++c) {
                f16x8 f;
#pragma unroll
                for (int e = 0; e < 8; ++e)
                    f[e] = (f16)(U1[(32 * c + quad * 8 + e) * 512 + n] * sc);
                wt[g][c] = f;
            }
#pragma unroll
            for (int c = 0; c < 2; ++c) {
                f16x8 f;
#pragma unroll
                for (int e = 0; e < 8; ++e)
                    f[e] = (f16)(W1[(32 * c + quad * 8 + e) * 512 + n] * sc);
                wt[g][4 + c] = f;
            }
        }
        // x[t=0] fragment: lane (quad,lid) holds x[batch=lid][k=quad*8+e], k<64
        xp = xh + (size_t)(b0 + lid) * TT * FF + quad * 8;
        xf0 = *(const f16x8*)xp;
        xf1 = *(const f16x8*)(xp + 32);
        xp += FF;                  // -> x[t=1]
    } else {
#pragma unroll
        for (int g = 0; g < 4; ++g) {
            const float sc = (g == 2) ? 1.f : L2E;
            const int n = 64 * g + 16 * j + lid;
#pragma unroll
            for (int rr = 0; rr < 4; ++rr)
                bsp[g][rr] = b2[64 * g + 16 * j + quad * 4 + rr] * sc;
#pragma unroll
            for (int c = 0; c < 4; ++c) {
                f16x8 f;
#pragma unroll
                for (int e = 0; e < 8; ++e)
                    f[e] = (f16)(W2[(32 * c + quad * 8 + e) * 256 + n] * sc);
                wt[g][c] = f;
            }
#pragma unroll
            for (int c = 0; c < 2; ++c) {
                f16x8 f;
#pragma unroll
                for (int e = 0; e < 8; ++e)
                    f[e] = (f16)(U2[(32 * c + quad * 8 + e) * 256 + n] * sc);
                wt[g][4 + c] = f;
            }
        }
    }
    __syncthreads();

    // one pipeline step; PAR = i&1 known at compile time => LDS immediates.
    auto step = [&](auto parc, int i) {
        constexpr int PAR = decltype(parc)::value;
        constexpr int PR = PAR ^ 1;   // h1[i-1]
        constexpr int PW = PAR;       // h1[i]
        constexpr int QR = PAR;       // h2[i-2]
        constexpr int QW = PAR ^ 1;   // h2[i-1]
        if (isL1) {
            f16x8 fr0 = *(const f16x8*)&h1b[PR][lid][quad * 8];
            f16x8 fr1 = *(const f16x8*)&h1b[PR][lid][32 + quad * 8];
            f16x8 fr2 = *(const f16x8*)&h1b[PR][lid][64 + quad * 8];
            f16x8 fr3 = *(const f16x8*)&h1b[PR][lid][96 + quad * 8];
            f32x4 acc[4];
#pragma unroll
            for (int g = 0; g < 4; ++g) {
                f32x4 a = mfma16(wt[g][0], fr0, bsp[g]);   // weights = A operand
                a = mfma16(wt[g][1], fr1, a);
                a = mfma16(wt[g][2], fr2, a);
                a = mfma16(wt[g][3], fr3, a);
                a = mfma16(wt[g][4], xf0, a);
                a = mfma16(wt[g][5], xf1, a);
                acc[g] = a;
            }
            // prefetch x[i+1] into the SAME regs after consumption; lands
            // during epilogue + barrier + next step's LDS reads (~1 step).
            if (i + 1 < TT) {
                xf0 = *(const f16x8*)xp;
                xf1 = *(const f16x8*)(xp + 32);
                xp += FF;
            }
            f16x4 hp;
#pragma unroll
            for (int r = 0; r < 4; ++r) {
                const float ig = sigm2(acc[0][r]);
                const float fg = sigm2(acc[1][r]);
                const float gg = fmaxf(acc[2][r], 0.f);
                const float og = sigm2(acc[3][r]);
                const float cc = fg * cs[r] + ig * gg;
                cs[r] = cc;
                hp[r] = (f16)(og * fmaxf(cc, 0.f));
            }
            *(f16x4*)&h1b[PW][lid][16 * w + quad * 4] = hp;   // packed b64
        } else {
            if (i >= 1) {
                f16x8 fr0 = *(const f16x8*)&h1b[PR][lid][quad * 8];
                f16x8 fr1 = *(const f16x8*)&h1b[PR][lid][32 + quad * 8];
                f16x8 fr2 = *(const f16x8*)&h1b[PR][lid][64 + quad * 8];
                f16x8 fr3 = *(const f16x8*)&h1b[PR][lid][96 + quad * 8];
                f16x8 fr4 = *(const f16x8*)&h2b[QR][lid][quad * 8];
                f16x8 fr5 = *(const f16x8*)&h2b[QR][lid][32 + quad * 8];
                f32x4 acc[4];
#pragma unroll
                for (int g = 0; g < 4; ++g) {
                    f32x4 a = mfma16(wt[g][0], fr0, bsp[g]);
                    a = mfma16(wt[g][1], fr1, a);
                    a = mfma16(wt[g][2], fr2, a);
                    a = mfma16(wt[g][3], fr3, a);
                    a = mfma16(wt[g][4], fr4, a);
                    a = mfma16(wt[g][5], fr5, a);
                    acc[g] = a;
                }
                f16x4 hp;
#pragma unroll
                for (int r = 0; r < 4; ++r) {
                    const float ig = sigm2(acc[0][r]);
                    const float fg = sigm2(acc[1][r]);
                    const float gg = fmaxf(acc[2][r], 0.f);
                    const float og = sigm2(acc[3][r]);
                    const float cc = fg * cs[r] + ig * gg;
                    cs[r] = cc;
                    hp[r] = (f16)(og * fmaxf(cc, 0.f));
                }
                *(f16x4*)&h2b[QW][lid][16 * j + quad * 4] = hp;   // packed b64
            }
        }
    };

    // ---------------- main loop, unrolled x2: ONE barrier per step ----------------
    for (int ii = 0; ii < TT; ii += 2) {
        step(std::integral_constant<int, 0>{}, ii);
        __syncthreads();
        step(std::integral_constant<int, 1>{}, ii + 1);
        __syncthreads();
    }

    // final pipeline step i=TT (even): L2 consumes h1[TT-1], exports h2 f32
    if (!isL1) {
        f16x8 fr0 = *(const f16x8*)&h1b[1][lid][quad * 8];
        f16x8 fr1 = *(const f16x8*)&h1b[1][lid][32 + quad * 8];
        f16x8 fr2 = *(const f16x8*)&h1b[1][lid][64 + quad * 8];
        f16x8 fr3 = *(const f16x8*)&h1b[1][lid][96 + quad * 8];
        f16x8 fr4 = *(const f16x8*)&h2b[0][lid][quad * 8];
        f16x8 fr5 = *(const f16x8*)&h2b[0][lid][32 + quad * 8];
        f32x4 acc[4];
#pragma unroll
        for (int g = 0; g < 4; ++g) {
            f32x4 a = mfma16(wt[g][0], fr0, bsp[g]);
            a = mfma16(wt[g][1], fr1, a);
            a = mfma16(wt[g][2], fr2, a);
            a = mfma16(wt[g][3], fr3, a);
            a = mfma16(wt[g][4], fr4, a);
            a = mfma16(wt[g][5], fr5, a);
            acc[g] = a;
        }
        float4 ho;
#pragma unroll
        for (int r = 0; r < 4; ++r) {
            const float ig = sigm2(acc[0][r]);
            const float fg = sigm2(acc[1][r]);
            const float gg = fmaxf(acc[2][r], 0.f);
            const float og = sigm2(acc[3][r]);
            const float cc = fg * cs[r] + ig * gg;
            (&ho.x)[r] = og * fmaxf(cc, 0.f);
        }
        *(float4*)&h2f[lid][16 * j + quad * 4] = ho;   // [batch][unit]
    }
    __syncthreads();

    // ---------------- dense head ----------------
    for (int idx = tid; idx < 16 * D1; idx += 768) {
        const int bq = idx / D1, p = idx % D1;
        float d = bd1[p];
#pragma unroll
        for (int k = 0; k < H2; ++k) d += h2f[bq][k] * Wd1[k * D1 + p];
        dsh[bq][p] = d * Wd2[p];
    }
    __syncthreads();
    if (tid < 16) {
        float o = bd2[0];
#pragma unroll
        for (int p = 0; p < D1; ++p) o += dsh[tid][p];
        out[b0 + tid] = o;
    }
}

extern "C" void kernel_launch(void* const* d_in, const int* in_sizes, int n_in,
                              void* d_out, int out_size, void* d_ws, size_t ws_size,
                              hipStream_t stream) {
    (void)in_sizes; (void)n_in; (void)out_size; (void)ws_size;
    const float* x   = (const float*)d_in[0];
    const float* W1  = (const float*)d_in[1];
    const float* U1  = (const float*)d_in[2];
    const float* b1  = (const float*)d_in[3];
    const float* W2  = (const float*)d_in[4];
    const float* U2  = (const float*)d_in[5];
    const float* b2  = (const float*)d_in[6];
    const float* Wd1 = (const float*)d_in[7];
    const float* bd1 = (const float*)d_in[8];
    const float* Wd2 = (const float*)d_in[9];
    const float* bd2 = (const float*)d_in[10];
    float* out = (float*)d_out;
    f16*   xh  = (f16*)d_ws;    // 512*512*64 f16 = 32 MiB scratch

    const int nx = 512 * 512 * 64;
    cvt_x_kernel<<<dim3(nx / (256 * 4)), dim3(256), 0, stream>>>(x, xh);
    lstm_pipe11<<<dim3(32), dim3(768), 0, stream>>>(
        xh, W1, U1, b1, W2, U2, b2, Wd1, bd1, Wd2, bd2, out);
}

// Round 14
// 685.096 us; speedup vs baseline: 1.2303x; 1.1779x over previous
//
#include <hip/hip_runtime.h>
#include <type_traits>

typedef _Float16 f16;
typedef _Float16 f16x4 __attribute__((ext_vector_type(4)));
typedef _Float16 f16x8 __attribute__((ext_vector_type(8)));
typedef float    f32x4 __attribute__((ext_vector_type(4)));

constexpr int TT = 512;   // timesteps
constexpr int FF = 64;    // input features
constexpr int H1 = 128;   // layer-1 hidden (512 gate cols)
constexpr int H2 = 64;    // layer-2 hidden (256 gate cols)
constexpr int D1 = 25;    // dense-1 width
constexpr int S1 = 136;   // h1 LDS row stride (f16)
constexpr int S2 = 72;    // h2 LDS row stride
constexpr int XC = 8;     // x timesteps per staged LDS chunk
constexpr float L2E = 1.44269504088896f;

// z pre-scaled by log2(e) at weight-load time: sigmoid = rcp(1 + 2^-z).
__device__ __forceinline__ float sigm2(float z) {
    return __builtin_amdgcn_rcpf(1.f + __builtin_amdgcn_exp2f(-z));
}

__device__ __forceinline__ f32x4 mfma16(f16x8 a, f16x8 b, f32x4 c) {
    return __builtin_amdgcn_mfma_f32_16x16x32_f16(a, b, c, 0, 0, 0);
}

__device__ __forceinline__ void gl_lds16(const f16* g, f16* l) {
    __builtin_amdgcn_global_load_lds(
        (const __attribute__((address_space(1))) unsigned int*)g,
        (__attribute__((address_space(3))) unsigned int*)l, 16, 0, 0);
}

// pre-pass: x fp32 -> f16 so staging is a raw byte copy.
__global__ void cvt_x_kernel(const float* __restrict__ x, f16* __restrict__ xh) {
    const size_t i = ((size_t)blockIdx.x * blockDim.x + threadIdx.x) * 4;
    const float4 v = *(const float4*)(x + i);
    f16x4 h; h[0] = (f16)v.x; h[1] = (f16)v.y; h[2] = (f16)v.z; h[3] = (f16)v.w;
    *(f16x4*)(xh + i) = h;
}

// R14 = R11 (best passing structure, kernel 618 us) + s_setprio 1 on the L1
// waves (serial critical chain) -- pure issue-arbitration bias, zero new
// instructions in the loop.
// 32 blocks x 768 threads (12 waves, 3/SIMD). Waves 0-7: layer-1 step i.
// Waves 8-11: layer-2 step i-1. Ping-pong h1/h2 LDS buffers => ONE barrier
// per step; compile-time parity; operand-swapped MFMA (weights = A operand,
// D rows = 4 consecutive gate cols per lane => packed ds_write_b64 + bias as
// MFMA C-init). x double-buffered in LDS via global_load_lds every 8 steps
// (drain amortized; per-step global loads are poison -- R13 evidence).
__global__ __launch_bounds__(768, 3)
void lstm_pipe12(const f16* __restrict__ xh, const float* __restrict__ W1,
                 const float* __restrict__ U1, const float* __restrict__ b1,
                 const float* __restrict__ W2, const float* __restrict__ U2,
                 const float* __restrict__ b2, const float* __restrict__ Wd1,
                 const float* __restrict__ bd1,const float* __restrict__ Wd2,
                 const float* __restrict__ bd2, float* __restrict__ out)
{
    const int tid  = threadIdx.x;
    const int w    = tid >> 6;      // wave 0..11
    const int lane = tid & 63;
    const int quad = lane >> 4;
    const int lid  = lane & 15;
    const int b0   = blockIdx.x * 16;
    const bool isL1 = (w < 8);
    const int  j    = isL1 ? w : (w - 8);

    __shared__ __align__(16) f16 h1b[2][16][S1];
    __shared__ __align__(16) f16 h2b[2][16][S2];
    // x chunk layout: [tl(8)][fseg(8)][row(16)] of 8-f16 (16 B) segments.
    __shared__ __align__(16) f16 xlds[2][XC * 8 * 16 * 8];
    __shared__ float h2f[16][H2];
    __shared__ float dsh[16][D1];

    for (int i = tid; i < 2 * 16 * S1 / 2; i += 768) ((unsigned*)h1b)[i] = 0u;
    for (int i = tid; i < 2 * 16 * S2 / 2; i += 768) ((unsigned*)h2b)[i] = 0u;

    // stage x chunk 0 (timesteps 0..7) into xlds[0]
    for (int s = tid; s < XC * 8 * 16; s += 768) {
        const int tl = s >> 7, fs = (s >> 4) & 7, row = s & 15;
        const f16* gp = xh + ((size_t)(b0 + row) * TT + tl) * FF + fs * 8;
        gl_lds16(gp, &xlds[0][(s >> 6) * 512]);
    }

    // ---- weight fragments wt[g][c] (A operand): lane holds col n=base+lid,
    // rows k = 32c + quad*8 + e. gates 0,1,3 (i,f,o) pre-scaled by log2e.
    // L1 (w<8):  chunks 0..3 = U1 (h1, K=128), 4..5 = W1 (x, K=64)
    // L2 (w>=8): chunks 0..3 = W2 (h1, K=128), 4..5 = U2 (h2, K=64)
    f16x8 wt[4][6];
    f32x4 bsp[4];     // bias for this lane's 4 consecutive gate cols (C-init)
    float cs[4] = {0.f, 0.f, 0.f, 0.f};

    if (isL1) {
#pragma unroll
        for (int g = 0; g < 4; ++g) {
            const float sc = (g == 2) ? 1.f : L2E;
            const int n = 128 * g + 16 * w + lid;
#pragma unroll
            for (int rr = 0; rr < 4; ++rr)
                bsp[g][rr] = b1[128 * g + 16 * w + quad * 4 + rr] * sc;
#pragma unroll
            for (int c = 0; c < 4; ++c) {
                f16x8 f;
#pragma unroll
                for (int e = 0; e < 8; ++e)
                    f[e] = (f16)(U1[(32 * c + quad * 8 + e) * 512 + n] * sc);
                wt[g][c] = f;
            }
#pragma unroll
            for (int c = 0; c < 2; ++c) {
                f16x8 f;
#pragma unroll
                for (int e = 0; e < 8; ++e)
                    f[e] = (f16)(W1[(32 * c + quad * 8 + e) * 512 + n] * sc);
                wt[g][4 + c] = f;
            }
        }
    } else {
#pragma unroll
        for (int g = 0; g < 4; ++g) {
            const float sc = (g == 2) ? 1.f : L2E;
            const int n = 64 * g + 16 * j + lid;
#pragma unroll
            for (int rr = 0; rr < 4; ++rr)
                bsp[g][rr] = b2[64 * g + 16 * j + quad * 4 + rr] * sc;
#pragma unroll
            for (int c = 0; c < 4; ++c) {
                f16x8 f;
#pragma unroll
                for (int e = 0; e < 8; ++e)
                    f[e] = (f16)(W2[(32 * c + quad * 8 + e) * 256 + n] * sc);
                wt[g][c] = f;
            }
#pragma unroll
            for (int c = 0; c < 2; ++c) {
                f16x8 f;
#pragma unroll
                for (int e = 0; e < 8; ++e)
                    f[e] = (f16)(U2[(32 * c + quad * 8 + e) * 256 + n] * sc);
                wt[g][4 + c] = f;
            }
        }
    }
    __syncthreads();   // also drains staging vmcnt

    // bias issue arbitration toward the serial L1 recurrence
    if (isL1) asm volatile("s_setprio 1");

    // one pipeline step; PAR = i&1 known at compile time => LDS immediates.
    // D[m=quad*4+r][n=lid]: m = 4 consecutive gate cols, n = batch row.
    auto step = [&](auto parc, int i) {
        constexpr int PAR = decltype(parc)::value;
        constexpr int PR = PAR ^ 1;   // h1[i-1]
        constexpr int PW = PAR;       // h1[i]
        constexpr int QR = PAR;       // h2[i-2]
        constexpr int QW = PAR ^ 1;   // h2[i-1]
        if (isL1) {
            const f16* xc = &xlds[(i >> 3) & 1][(i & 7) * 1024];
            f16x8 fr0 = *(const f16x8*)&h1b[PR][lid][quad * 8];
            f16x8 fr1 = *(const f16x8*)&h1b[PR][lid][32 + quad * 8];
            f16x8 fr2 = *(const f16x8*)&h1b[PR][lid][64 + quad * 8];
            f16x8 fr3 = *(const f16x8*)&h1b[PR][lid][96 + quad * 8];
            f16x8 xf0 = *(const f16x8*)&xc[(quad * 16 + lid) * 8];
            f16x8 xf1 = *(const f16x8*)&xc[((4 + quad) * 16 + lid) * 8];
            f32x4 acc[4];
#pragma unroll
            for (int g = 0; g < 4; ++g) {
                f32x4 a = mfma16(wt[g][0], fr0, bsp[g]);   // weights = A operand
                a = mfma16(wt[g][1], fr1, a);
                a = mfma16(wt[g][2], fr2, a);
                a = mfma16(wt[g][3], fr3, a);
                a = mfma16(wt[g][4], xf0, a);
                a = mfma16(wt[g][5], xf1, a);
                acc[g] = a;
            }
            f16x4 hp;
#pragma unroll
            for (int r = 0; r < 4; ++r) {
                const float ig = sigm2(acc[0][r]);
                const float fg = sigm2(acc[1][r]);
                const float gg = fmaxf(acc[2][r], 0.f);
                const float og = sigm2(acc[3][r]);
                const float cc = fg * cs[r] + ig * gg;
                cs[r] = cc;
                hp[r] = (f16)(og * fmaxf(cc, 0.f));
            }
            *(f16x4*)&h1b[PW][lid][16 * w + quad * 4] = hp;   // packed b64
        } else {
            if (i >= 1) {
                f16x8 fr0 = *(const f16x8*)&h1b[PR][lid][quad * 8];
                f16x8 fr1 = *(const f16x8*)&h1b[PR][lid][32 + quad * 8];
                f16x8 fr2 = *(const f16x8*)&h1b[PR][lid][64 + quad * 8];
                f16x8 fr3 = *(const f16x8*)&h1b[PR][lid][96 + quad * 8];
                f16x8 fr4 = *(const f16x8*)&h2b[QR][lid][quad * 8];
                f16x8 fr5 = *(const f16x8*)&h2b[QR][lid][32 + quad * 8];
                f32x4 acc[4];
#pragma unroll
                for (int g = 0; g < 4; ++g) {
                    f32x4 a = mfma16(wt[g][0], fr0, bsp[g]);
                    a = mfma16(wt[g][1], fr1, a);
                    a = mfma16(wt[g][2], fr2, a);
                    a = mfma16(wt[g][3], fr3, a);
                    a = mfma16(wt[g][4], fr4, a);
                    a = mfma16(wt[g][5], fr5, a);
                    acc[g] = a;
                }
                f16x4 hp;
#pragma unroll
                for (int r = 0; r < 4; ++r) {
                    const float ig = sigm2(acc[0][r]);
                    const float fg = sigm2(acc[1][r]);
                    const float gg = fmaxf(acc[2][r], 0.f);
                    const float og = sigm2(acc[3][r]);
                    const float cc = fg * cs[r] + ig * gg;
                    cs[r] = cc;
                    hp[r] = (f16)(og * fmaxf(cc, 0.f));
                }
                *(f16x4*)&h2b[QW][lid][16 * j + quad * 4] = hp;   // packed b64
            }
        }
    };

    // ---------------- main loop, unrolled x2: ONE barrier per step ----------------
    for (int ii = 0; ii < TT; ii += 2) {
        if ((ii & (XC - 1)) == 0 && ii + XC < TT) {
            const int nc = (ii >> 3) + 1;
            f16* dst = xlds[nc & 1];
            for (int s = tid; s < XC * 8 * 16; s += 768) {
                const int tl = s >> 7, fs = (s >> 4) & 7, row = s & 15;
                const f16* gp = xh + ((size_t)(b0 + row) * TT + (nc * XC + tl)) * FF + fs * 8;
                gl_lds16(gp, &dst[(s >> 6) * 512]);
            }
        }
        step(std::integral_constant<int, 0>{}, ii);
        __syncthreads();
        step(std::integral_constant<int, 1>{}, ii + 1);
        __syncthreads();
    }

    if (isL1) asm volatile("s_setprio 0");

    // final pipeline step i=TT (even): L2 consumes h1[TT-1], exports h2 f32
    if (!isL1) {
        f16x8 fr0 = *(const f16x8*)&h1b[1][lid][quad * 8];
        f16x8 fr1 = *(const f16x8*)&h1b[1][lid][32 + quad * 8];
        f16x8 fr2 = *(const f16x8*)&h1b[1][lid][64 + quad * 8];
        f16x8 fr3 = *(const f16x8*)&h1b[1][lid][96 + quad * 8];
        f16x8 fr4 = *(const f16x8*)&h2b[0][lid][quad * 8];
        f16x8 fr5 = *(const f16x8*)&h2b[0][lid][32 + quad * 8];
        f32x4 acc[4];
#pragma unroll
        for (int g = 0; g < 4; ++g) {
            f32x4 a = mfma16(wt[g][0], fr0, bsp[g]);
            a = mfma16(wt[g][1], fr1, a);
            a = mfma16(wt[g][2], fr2, a);
            a = mfma16(wt[g][3], fr3, a);
            a = mfma16(wt[g][4], fr4, a);
            a = mfma16(wt[g][5], fr5, a);
            acc[g] = a;
        }
        float4 ho;
#pragma unroll
        for (int r = 0; r < 4; ++r) {
            const float ig = sigm2(acc[0][r]);
            const float fg = sigm2(acc[1][r]);
            const float gg = fmaxf(acc[2][r], 0.f);
            const float og = sigm2(acc[3][r]);
            const float cc = fg * cs[r] + ig * gg;
            (&ho.x)[r] = og * fmaxf(cc, 0.f);
        }
        *(float4*)&h2f[lid][16 * j + quad * 4] = ho;   // [batch][unit]
    }
    __syncthreads();

    // ---------------- dense head ----------------
    for (int idx = tid; idx < 16 * D1; idx += 768) {
        const int bq = idx / D1, p = idx % D1;
        float d = bd1[p];
#pragma unroll
        for (int k = 0; k < H2; ++k) d += h2f[bq][k] * Wd1[k * D1 + p];
        dsh[bq][p] = d * Wd2[p];
    }
    __syncthreads();
    if (tid < 16) {
        float o = bd2[0];
#pragma unroll
        for (int p = 0; p < D1; ++p) o += dsh[tid][p];
        out[b0 + tid] = o;
    }
}

extern "C" void kernel_launch(void* const* d_in, const int* in_sizes, int n_in,
                              void* d_out, int out_size, void* d_ws, size_t ws_size,
                              hipStream_t stream) {
    (void)in_sizes; (void)n_in; (void)out_size; (void)ws_size;
    const float* x   = (const float*)d_in[0];
    const float* W1  = (const float*)d_in[1];
    const float* U1  = (const float*)d_in[2];
    const float* b1  = (const float*)d_in[3];
    const float* W2  = (const float*)d_in[4];
    const float* U2  = (const float*)d_in[5];
    const float* b2  = (const float*)d_in[6];
    const float* Wd1 = (const float*)d_in[7];
    const float* bd1 = (const float*)d_in[8];
    const float* Wd2 = (const float*)d_in[9];
    const float* bd2 = (const float*)d_in[10];
    float* out = (float*)d_out;
    f16*   xh  = (f16*)d_ws;    // 512*512*64 f16 = 32 MiB scratch

    const int nx = 512 * 512 * 64;
    cvt_x_kernel<<<dim3(nx / (256 * 4)), dim3(256), 0, stream>>>(x, xh);
    lstm_pipe12<<<dim3(32), dim3(768), 0, stream>>>(
        xh, W1, U1, b1, W2, U2, b2, Wd1, bd1, Wd2, bd2, out);
}